// Round 6
// baseline (1185.462 us; speedup 1.0000x reference)
//
#include <hip/hip_runtime.h>

#define NGRAPH 16
#define NPG    2048
#define NNODE  (NGRAPH*NPG)      // 32768
#define DIN    128
#define DEMB   64
#define NEDGE  (NNODE*16)        // 524288
#define QCAP   4096

typedef float f32x4 __attribute__((ext_vector_type(4)));

__device__ __forceinline__ float wsum(float v) {
    #pragma unroll
    for (int m = 1; m < 64; m <<= 1) v += __shfl_xor(v, m, 64);
    return v;
}
__device__ __forceinline__ float wmax(float v) {
    #pragma unroll
    for (int m = 1; m < 64; m <<= 1) v = fmaxf(v, __shfl_xor(v, m, 64));
    return v;
}

// ---------------- Kernel 1: h = x@W_self, xn = x@W_nei ----------------
__global__ __launch_bounds__(256) void k_inproj(
    const float* __restrict__ x, const float* __restrict__ Wself,
    const float* __restrict__ Wnei, float* __restrict__ h, float* __restrict__ xn)
{
    __shared__ float ws[DIN*DEMB];   // 32 KB
    __shared__ float wn[DIN*DEMB];   // 32 KB
    int tid = threadIdx.x;
    int n0 = blockIdx.x * 32;
    #pragma unroll
    for (int k = 0; k < 8; ++k) {
        ((float4*)ws)[tid + k*256] = ((const float4*)Wself)[tid + k*256];
        ((float4*)wn)[tid + k*256] = ((const float4*)Wnei)[tid + k*256];
    }
    __syncthreads();
    int nl = tid >> 3, og = (tid & 7) * 8;
    const float* xr = x + (size_t)(n0 + nl) * DIN;
    float ah[8] = {0,0,0,0,0,0,0,0};
    float an[8] = {0,0,0,0,0,0,0,0};
    for (int d4 = 0; d4 < DIN/4; ++d4) {
        float4 xv = *(const float4*)(xr + d4*4);
        #pragma unroll
        for (int dd = 0; dd < 4; ++dd) {
            float xs = (dd==0)?xv.x:(dd==1)?xv.y:(dd==2)?xv.z:xv.w;
            int d = d4*4 + dd;
            float4 a = *(const float4*)&ws[d*DEMB + og];
            float4 b = *(const float4*)&ws[d*DEMB + og + 4];
            ah[0] += xs*a.x; ah[1] += xs*a.y; ah[2] += xs*a.z; ah[3] += xs*a.w;
            ah[4] += xs*b.x; ah[5] += xs*b.y; ah[6] += xs*b.z; ah[7] += xs*b.w;
            float4 c = *(const float4*)&wn[d*DEMB + og];
            float4 e = *(const float4*)&wn[d*DEMB + og + 4];
            an[0] += xs*c.x; an[1] += xs*c.y; an[2] += xs*c.z; an[3] += xs*c.w;
            an[4] += xs*e.x; an[5] += xs*e.y; an[6] += xs*e.z; an[7] += xs*e.w;
        }
    }
    size_t o = (size_t)(n0 + nl)*DEMB + og;
    *(float4*)&h[o]    = make_float4(ah[0],ah[1],ah[2],ah[3]);
    *(float4*)&h[o+4]  = make_float4(ah[4],ah[5],ah[6],ah[7]);
    *(float4*)&xn[o]   = make_float4(an[0],an[1],an[2],an[3]);
    *(float4*)&xn[o+4] = make_float4(an[4],an[5],an[6],an[7]);
}

// ---------------- Kernel 2: edge aggregation, LDS-binned (no global atomics) ----------------
__global__ __launch_bounds__(1024) void k_agg(
    const int* __restrict__ ei, const float* __restrict__ xn,
    float* __restrict__ agg, float* __restrict__ deg)
{
    __shared__ float accL[128*64];   // 32 KB
    __shared__ float degL[128];
    __shared__ int   queue[QCAP];    // 16 KB
    __shared__ int   qcnt;
    int tid = threadIdx.x;
    int g   = blockIdx.x >> 4;       // graph
    int dlo = (blockIdx.x & 15) * 128;
    for (int k = tid; k < 128*64; k += 1024) accL[k] = 0.f;
    if (tid < 128) degL[tid] = 0.f;
    if (tid == 0) qcnt = 0;
    __syncthreads();
    int e0 = g * (NPG*16);
    int gbase = g * NPG;
    for (int k = 0; k < 32; ++k) {
        int e = e0 + k*1024 + tid;
        int dst = ei[NEDGE + e];
        int dl = dst - gbase - dlo;
        if ((unsigned)dl < 128u) {
            int src = ei[e];                 // global node id < 32768, fits 16 bits
            int qi = atomicAdd(&qcnt, 1);
            if (qi < QCAP) queue[qi] = (dl << 16) | src;
        }
    }
    __syncthreads();
    int qn = qcnt < QCAP ? qcnt : QCAP;
    int w = tid >> 6, l = tid & 63;
    int i = w;
    // 8-deep gather pipeline for latency hiding
    for (; i + 112 < qn; i += 128) {
        int p[8]; float v[8];
        #pragma unroll
        for (int k = 0; k < 8; ++k) p[k] = queue[i + 16*k];
        #pragma unroll
        for (int k = 0; k < 8; ++k) v[k] = xn[(size_t)(p[k] & 0xffff)*64 + l];
        #pragma unroll
        for (int k = 0; k < 8; ++k) {
            atomicAdd(&accL[(p[k] >> 16)*64 + l], v[k]);
            if (l == 0) atomicAdd(&degL[p[k] >> 16], 1.f);
        }
    }
    for (; i < qn; i += 16) {
        int p0 = queue[i];
        float v0 = xn[(size_t)(p0 & 0xffff)*64 + l];
        atomicAdd(&accL[(p0 >> 16)*64 + l], v0);
        if (l == 0) atomicAdd(&degL[p0 >> 16], 1.f);
    }
    __syncthreads();
    size_t obase = (size_t)(gbase + dlo) * 64;
    for (int k = tid; k < 128*64; k += 1024) agg[obase + k] = accL[k];
    if (tid < 128) deg[gbase + dlo + tid] = degL[tid];
}

// ---- Kernel 3: fused epilogue + transpose:
//      x_aux = relu(h + agg/max(deg,1) + b); sq = ||x_aux||^2; xtg = x_aux^T ----
__global__ __launch_bounds__(256) void k_epitr(
    const float* __restrict__ h, const float* __restrict__ agg,
    const float* __restrict__ deg, const float* __restrict__ bias,
    float* __restrict__ xaux, float* __restrict__ sqv, float* __restrict__ xtg)
{
    __shared__ float tl[64*65];
    int tid = threadIdx.x;
    int n0 = blockIdx.x * 64;
    int w = tid >> 6, l = tid & 63;
    #pragma unroll
    for (int k = 0; k < 16; ++k) {
        int n = k*4 + w;                         // local node, wave-uniform
        float dg = fmaxf(deg[n0 + n], 1.f);
        size_t ge = (size_t)(n0 + n)*64 + l;
        float v = h[ge] + agg[ge] / dg + bias[l];
        v = fmaxf(v, 0.f);
        xaux[ge] = v;
        float s = wsum(v*v);
        if (l == 0) sqv[n0 + n] = s;
        tl[n*65 + l] = v;
    }
    __syncthreads();
    #pragma unroll
    for (int k = 0; k < 16; ++k) {
        int f = tid + k*256;
        xtg[(size_t)(f >> 6)*NNODE + n0 + (f & 63)] = tl[(f & 63)*65 + (f >> 6)];
    }
}

// ---------------- Kernel 4: fused pairwise distance + noise + LN-ish + entmax15 ----------------
// 16 rows/block, 512 threads (8 waves). GEMM layout: wave = 256-col strip, lane = 4 cols,
// acc[16][4]. Transition through 32KB LDS in 4 rounds of 4 rows, interleaved with two
// entmax passes so only one z[8][4] is live at a time. Wave w owns rows {w, w+8}.
#define PFMA(R, XI) { float xs_ = (XI); acc[R][0] += xs_*xj.x; acc[R][1] += xs_*xj.y; acc[R][2] += xs_*xj.z; acc[R][3] += xs_*xj.w; }

__device__ __forceinline__ void entmax_row(
    float (&z)[8][4], int l, size_t ro, float* __restrict__ outA, float* __restrict__ outL)
{
    // row stats: mu, sd, max (on logits held in z)
    float s = 0.f;
    #pragma unroll
    for (int k = 0; k < 8; ++k) { s += z[k][0]; s += z[k][1]; s += z[k][2]; s += z[k][3]; }
    s = wsum(s);
    float mu = s * (1.f/2048.f);
    float vs = 0.f;
    #pragma unroll
    for (int k = 0; k < 8; ++k) {
        #pragma unroll
        for (int c = 0; c < 4; ++c) { float t = z[k][c] - mu; vs += t*t; }
    }
    vs = wsum(vs);
    float sd = sqrtf(vs * (1.f/2048.f));
    float mx = -1e30f;
    #pragma unroll
    for (int k = 0; k < 8; ++k) {
        #pragma unroll
        for (int c = 0; c < 4; ++c) mx = fmaxf(mx, z[k][c]);
    }
    mx = wmax(mx);

    // z = 0.5*GAMMA*(lg - mu)/(sd+1e-5) - max(...) == cc*(lg - lgmax)
    float cc = 2.5f / (sd + 1e-5f);
    #pragma unroll
    for (int k = 0; k < 8; ++k) {
        #pragma unroll
        for (int c = 0; c < 4; ++c) z[k][c] = cc * (z[k][c] - mx);
    }

    // candidate extraction: only z > -1 can be in support (tau* >= zmax-1 = -1)
    float c0=-2.f, c1=-2.f, c2=-2.f, c3=-2.f; int cnt = 0;
    #pragma unroll
    for (int k = 0; k < 8; ++k) {
        #pragma unroll
        for (int c = 0; c < 4; ++c) {
            float zv = z[k][c];
            bool p = zv > -1.f;
            c3 = p ? c2 : c3; c2 = p ? c1 : c2; c1 = p ? c0 : c1; c0 = p ? zv : c0;
            cnt += p ? 1 : 0;
        }
    }
    unsigned long long ovf = __ballot(cnt > 4);

    // bisection on S(tau) = sum max(z-tau,0)^2 = 1, tau in [-1, 0]
    float lo = -1.f, hi = 0.f;
    if (ovf == 0ull) {
        for (int it = 0; it < 25; ++it) {
            float mid = 0.5f*(lo+hi);
            float p, S;
            p = fmaxf(c0-mid,0.f); S  = p*p;
            p = fmaxf(c1-mid,0.f); S += p*p;
            p = fmaxf(c2-mid,0.f); S += p*p;
            p = fmaxf(c3-mid,0.f); S += p*p;
            S = wsum(S);
            bool ge = S >= 1.f;
            lo = ge ? mid : lo; hi = ge ? hi : mid;
        }
    } else {
        for (int it = 0; it < 25; ++it) {
            float mid = 0.5f*(lo+hi);
            float S = 0.f;
            #pragma unroll
            for (int k = 0; k < 8; ++k) {
                #pragma unroll
                for (int c = 0; c < 4; ++c) { float p = fmaxf(z[k][c]-mid, 0.f); S += p*p; }
            }
            S = wsum(S);
            bool ge = S >= 1.f;
            lo = ge ? mid : lo; hi = ge ? hi : mid;
        }
    }
    float tmid = 0.5f*(lo+hi);

    // exact tau from identified support (reference's closed form)
    float k1 = 0.f, s1 = 0.f, q1 = 0.f;
    if (ovf == 0ull) {
        bool in;
        in = c0 > tmid; k1 += in?1.f:0.f; s1 += in?c0:0.f; q1 += in?c0*c0:0.f;
        in = c1 > tmid; k1 += in?1.f:0.f; s1 += in?c1:0.f; q1 += in?c1*c1:0.f;
        in = c2 > tmid; k1 += in?1.f:0.f; s1 += in?c2:0.f; q1 += in?c2*c2:0.f;
        in = c3 > tmid; k1 += in?1.f:0.f; s1 += in?c3:0.f; q1 += in?c3*c3:0.f;
    } else {
        #pragma unroll
        for (int k = 0; k < 8; ++k) {
            #pragma unroll
            for (int c = 0; c < 4; ++c) {
                float zv = z[k][c];
                bool in = zv > tmid;
                k1 += in?1.f:0.f; s1 += in?zv:0.f; q1 += in?zv*zv:0.f;
            }
        }
    }
    k1 = wsum(k1); s1 = wsum(s1); q1 = wsum(q1);
    float kin  = 1.f / k1;
    float mean = s1 * kin;
    float ssv  = q1 - s1*s1*kin;
    float tau  = mean - sqrtf(fmaxf((1.f - ssv)*kin, 0.f));

    // outputs: A = clip(z - tau, 0)^2 ; logprobs = log(A + 1e-6); non-temporal (write-once)
    #pragma unroll
    for (int k = 0; k < 8; ++k) {
        float p;
        f32x4 a, lg;
        p = fmaxf(z[k][0]-tau, 0.f); a.x = p*p;
        p = fmaxf(z[k][1]-tau, 0.f); a.y = p*p;
        p = fmaxf(z[k][2]-tau, 0.f); a.z = p*p;
        p = fmaxf(z[k][3]-tau, 0.f); a.w = p*p;
        lg.x = __logf(a.x+1e-6f); lg.y = __logf(a.y+1e-6f);
        lg.z = __logf(a.z+1e-6f); lg.w = __logf(a.w+1e-6f);
        __builtin_nontemporal_store(a,  (f32x4*)&outA[ro + k*256 + (l << 2)]);
        __builtin_nontemporal_store(lg, (f32x4*)&outL[ro + k*256 + (l << 2)]);
    }
}

__global__ __launch_bounds__(512, 4) void k_pair(
    const float* __restrict__ xtg, const float* __restrict__ xaux,
    const float* __restrict__ sq, const float* __restrict__ noise,
    float* __restrict__ outA, float* __restrict__ outL)
{
    __shared__ float buf[4*2048];    // 32 KB transition buffer
    __shared__ float xit[64*16];     // 4 KB, d-major: xit[d*16 + r]
    __shared__ float sqi[16];
    int tid = threadIdx.x;
    int b  = blockIdx.x >> 7;        // 128 row-blocks per graph
    int r0 = (blockIdx.x & 127) << 4;
    {
        int e = tid;                 // e = d*16 + r
        xit[e] = xaux[(size_t)(b*NPG + r0 + (e & 15))*64 + (e >> 4)];
        e = tid + 512;
        xit[e] = xaux[(size_t)(b*NPG + r0 + (e & 15))*64 + (e >> 4)];
        if (tid < 16) sqi[tid] = sq[b*NPG + r0 + tid];
    }
    __syncthreads();
    int w = tid >> 6, l = tid & 63;
    int jb = b*NPG + (w << 8) + (l << 2);

    float acc[16][4];
    #pragma unroll
    for (int r = 0; r < 16; ++r) { acc[r][0]=0.f; acc[r][1]=0.f; acc[r][2]=0.f; acc[r][3]=0.f; }

    const float* xp = xtg + jb;
    #pragma unroll 2
    for (int d = 0; d < 64; ++d) {
        float4 xj = *(const float4*)(xp + (size_t)d*NNODE);
        const float4* xi = (const float4*)&xit[d*16];
        float4 x0 = xi[0], x1 = xi[1], x2 = xi[2], x3 = xi[3];
        PFMA( 0,x0.x) PFMA( 1,x0.y) PFMA( 2,x0.z) PFMA( 3,x0.w)
        PFMA( 4,x1.x) PFMA( 5,x1.y) PFMA( 6,x1.z) PFMA( 7,x1.w)
        PFMA( 8,x2.x) PFMA( 9,x2.y) PFMA(10,x2.z) PFMA(11,x2.w)
        PFMA(12,x3.x) PFMA(13,x3.y) PFMA(14,x3.z) PFMA(15,x3.w)
    }

    // logits = -sqrt(clip(sq_i + sq_j - 2*dot, 0) + 1e-12) + noise (in-place in acc)
    float4 sj = *(const float4*)&sq[jb];
    #pragma unroll
    for (int r = 0; r < 16; ++r) {
        f32x4 nz = __builtin_nontemporal_load(
            (const f32x4*)(noise + (size_t)(b*NPG + r0 + r)*NPG + (w << 8) + (l << 2)));
        float si = sqi[r];
        acc[r][0] = nz.x - sqrtf(fmaxf(si + sj.x - 2.f*acc[r][0], 0.f) + 1e-12f);
        acc[r][1] = nz.y - sqrtf(fmaxf(si + sj.y - 2.f*acc[r][1], 0.f) + 1e-12f);
        acc[r][2] = nz.z - sqrtf(fmaxf(si + sj.z - 2.f*acc[r][2], 0.f) + 1e-12f);
        acc[r][3] = nz.w - sqrtf(fmaxf(si + sj.w - 2.f*acc[r][3], 0.f) + 1e-12f);
    }

    int col = (w << 8) + (l << 2);
    int wr = w & 3;
    float z[8][4];

    // round 0: rows 0-3 -> waves 0-3
    #pragma unroll
    for (int r = 0; r < 4; ++r)
        *(float4*)&buf[r*2048 + col] = make_float4(acc[r][0],acc[r][1],acc[r][2],acc[r][3]);
    __syncthreads();
    if (w < 4) {
        #pragma unroll
        for (int k = 0; k < 8; ++k) {
            float4 t = *(const float4*)&buf[wr*2048 + k*256 + (l << 2)];
            z[k][0]=t.x; z[k][1]=t.y; z[k][2]=t.z; z[k][3]=t.w;
        }
    }
    __syncthreads();
    // round 1: rows 4-7 -> waves 4-7
    #pragma unroll
    for (int r = 0; r < 4; ++r)
        *(float4*)&buf[r*2048 + col] = make_float4(acc[r+4][0],acc[r+4][1],acc[r+4][2],acc[r+4][3]);
    __syncthreads();
    if (w >= 4) {
        #pragma unroll
        for (int k = 0; k < 8; ++k) {
            float4 t = *(const float4*)&buf[wr*2048 + k*256 + (l << 2)];
            z[k][0]=t.x; z[k][1]=t.y; z[k][2]=t.z; z[k][3]=t.w;
        }
    }
    __syncthreads();
    // entmax pass 1: wave w handles row r0+w (registers + global only)
    entmax_row(z, l, (size_t)(b*NPG + r0 + w) * NPG, outA, outL);

    // round 2: rows 8-11 -> waves 0-3
    #pragma unroll
    for (int r = 0; r < 4; ++r)
        *(float4*)&buf[r*2048 + col] = make_float4(acc[r+8][0],acc[r+8][1],acc[r+8][2],acc[r+8][3]);
    __syncthreads();
    if (w < 4) {
        #pragma unroll
        for (int k = 0; k < 8; ++k) {
            float4 t = *(const float4*)&buf[wr*2048 + k*256 + (l << 2)];
            z[k][0]=t.x; z[k][1]=t.y; z[k][2]=t.z; z[k][3]=t.w;
        }
    }
    __syncthreads();
    // round 3: rows 12-15 -> waves 4-7
    #pragma unroll
    for (int r = 0; r < 4; ++r)
        *(float4*)&buf[r*2048 + col] = make_float4(acc[r+12][0],acc[r+12][1],acc[r+12][2],acc[r+12][3]);
    __syncthreads();
    if (w >= 4) {
        #pragma unroll
        for (int k = 0; k < 8; ++k) {
            float4 t = *(const float4*)&buf[wr*2048 + k*256 + (l << 2)];
            z[k][0]=t.x; z[k][1]=t.y; z[k][2]=t.z; z[k][3]=t.w;
        }
    }
    // entmax pass 2: wave w handles row r0+8+w
    entmax_row(z, l, (size_t)(b*NPG + r0 + 8 + w) * NPG, outA, outL);
}

// ---------------- host ----------------
extern "C" void kernel_launch(void* const* d_in, const int* in_sizes, int n_in,
                              void* d_out, int out_size, void* d_ws, size_t ws_size,
                              hipStream_t stream)
{
    (void)in_sizes; (void)n_in; (void)out_size; (void)ws_size;
    const float* x     = (const float*)d_in[0];
    const int*   ei    = (const int*)d_in[1];
    const float* Wself = (const float*)d_in[4];
    const float* Wnei  = (const float*)d_in[5];
    const float* bias  = (const float*)d_in[6];
    const float* noise = (const float*)d_in[7];
    float* out = (float*)d_out;
    float* ws  = (float*)d_ws;

    // ws layout (floats), peak ~33.8 MB: h xn agg deg sq xtg
    // (xtg no longer aliases h: k_epitr reads h and writes xtg in the same kernel)
    float* h    = ws;
    float* xn   = ws + 2097152;
    float* agg  = ws + 4194304;
    float* deg  = ws + 6291456;
    float* sqv  = ws + 6324224;
    float* xtg  = ws + 6356992;

    float* xaux = out;                 // [32768][64]
    float* outA = out + 2097152;       // [16][2048][2048]
    float* outL = out + 69206016;      // [16][2048][2048]

    hipLaunchKernelGGL(k_inproj, dim3(1024), dim3(256),  0, stream, x, Wself, Wnei, h, xn);
    hipLaunchKernelGGL(k_agg,    dim3(256),  dim3(1024), 0, stream, ei, xn, agg, deg);
    hipLaunchKernelGGL(k_epitr,  dim3(512),  dim3(256),  0, stream, h, agg, deg, bias, xaux, sqv, xtg);
    hipLaunchKernelGGL(k_pair,   dim3(2048), dim3(512),  0, stream, xtg, xaux, sqv, noise, outA, outL);
}

// Round 8
// 1148.166 us; speedup vs baseline: 1.0325x; 1.0325x over previous
//
#include <hip/hip_runtime.h>

#define NGRAPH 16
#define NPG    2048
#define NNODE  (NGRAPH*NPG)      // 32768
#define DIN    128
#define DEMB   64
#define NEDGE  (NNODE*16)        // 524288
#define QCAP   4096

typedef float f32x4 __attribute__((ext_vector_type(4)));

__device__ __forceinline__ float wsum(float v) {
    #pragma unroll
    for (int m = 1; m < 64; m <<= 1) v += __shfl_xor(v, m, 64);
    return v;
}
__device__ __forceinline__ float wmax(float v) {
    #pragma unroll
    for (int m = 1; m < 64; m <<= 1) v = fmaxf(v, __shfl_xor(v, m, 64));
    return v;
}

// ---------------- Kernel 1: h = x@W_self, xn = x@W_nei ----------------
__global__ __launch_bounds__(256) void k_inproj(
    const float* __restrict__ x, const float* __restrict__ Wself,
    const float* __restrict__ Wnei, float* __restrict__ h, float* __restrict__ xn)
{
    __shared__ float ws[DIN*DEMB];   // 32 KB
    __shared__ float wn[DIN*DEMB];   // 32 KB
    int tid = threadIdx.x;
    int n0 = blockIdx.x * 32;
    #pragma unroll
    for (int k = 0; k < 8; ++k) {
        ((float4*)ws)[tid + k*256] = ((const float4*)Wself)[tid + k*256];
        ((float4*)wn)[tid + k*256] = ((const float4*)Wnei)[tid + k*256];
    }
    __syncthreads();
    int nl = tid >> 3, og = (tid & 7) * 8;
    const float* xr = x + (size_t)(n0 + nl) * DIN;
    float ah[8] = {0,0,0,0,0,0,0,0};
    float an[8] = {0,0,0,0,0,0,0,0};
    for (int d4 = 0; d4 < DIN/4; ++d4) {
        float4 xv = *(const float4*)(xr + d4*4);
        #pragma unroll
        for (int dd = 0; dd < 4; ++dd) {
            float xs = (dd==0)?xv.x:(dd==1)?xv.y:(dd==2)?xv.z:xv.w;
            int d = d4*4 + dd;
            float4 a = *(const float4*)&ws[d*DEMB + og];
            float4 b = *(const float4*)&ws[d*DEMB + og + 4];
            ah[0] += xs*a.x; ah[1] += xs*a.y; ah[2] += xs*a.z; ah[3] += xs*a.w;
            ah[4] += xs*b.x; ah[5] += xs*b.y; ah[6] += xs*b.z; ah[7] += xs*b.w;
            float4 c = *(const float4*)&wn[d*DEMB + og];
            float4 e = *(const float4*)&wn[d*DEMB + og + 4];
            an[0] += xs*c.x; an[1] += xs*c.y; an[2] += xs*c.z; an[3] += xs*c.w;
            an[4] += xs*e.x; an[5] += xs*e.y; an[6] += xs*e.z; an[7] += xs*e.w;
        }
    }
    size_t o = (size_t)(n0 + nl)*DEMB + og;
    *(float4*)&h[o]    = make_float4(ah[0],ah[1],ah[2],ah[3]);
    *(float4*)&h[o+4]  = make_float4(ah[4],ah[5],ah[6],ah[7]);
    *(float4*)&xn[o]   = make_float4(an[0],an[1],an[2],an[3]);
    *(float4*)&xn[o+4] = make_float4(an[4],an[5],an[6],an[7]);
}

// ---------------- Kernel 2: edge aggregation, LDS-binned (no global atomics) ----------------
__global__ __launch_bounds__(1024) void k_agg(
    const int* __restrict__ ei, const float* __restrict__ xn,
    float* __restrict__ agg, float* __restrict__ deg)
{
    __shared__ float accL[128*64];   // 32 KB
    __shared__ float degL[128];
    __shared__ int   queue[QCAP];    // 16 KB
    __shared__ int   qcnt;
    int tid = threadIdx.x;
    int g   = blockIdx.x >> 4;       // graph
    int dlo = (blockIdx.x & 15) * 128;
    for (int k = tid; k < 128*64; k += 1024) accL[k] = 0.f;
    if (tid < 128) degL[tid] = 0.f;
    if (tid == 0) qcnt = 0;
    __syncthreads();
    int e0 = g * (NPG*16);
    int gbase = g * NPG;
    for (int k = 0; k < 32; ++k) {
        int e = e0 + k*1024 + tid;
        int dst = ei[NEDGE + e];
        int dl = dst - gbase - dlo;
        if ((unsigned)dl < 128u) {
            int src = ei[e];                 // global node id < 32768, fits 16 bits
            int qi = atomicAdd(&qcnt, 1);
            if (qi < QCAP) queue[qi] = (dl << 16) | src;
        }
    }
    __syncthreads();
    int qn = qcnt < QCAP ? qcnt : QCAP;
    int w = tid >> 6, l = tid & 63;
    int i = w;
    // 8-deep gather pipeline for latency hiding
    for (; i + 112 < qn; i += 128) {
        int p[8]; float v[8];
        #pragma unroll
        for (int k = 0; k < 8; ++k) p[k] = queue[i + 16*k];
        #pragma unroll
        for (int k = 0; k < 8; ++k) v[k] = xn[(size_t)(p[k] & 0xffff)*64 + l];
        #pragma unroll
        for (int k = 0; k < 8; ++k) {
            atomicAdd(&accL[(p[k] >> 16)*64 + l], v[k]);
            if (l == 0) atomicAdd(&degL[p[k] >> 16], 1.f);
        }
    }
    for (; i < qn; i += 16) {
        int p0 = queue[i];
        float v0 = xn[(size_t)(p0 & 0xffff)*64 + l];
        atomicAdd(&accL[(p0 >> 16)*64 + l], v0);
        if (l == 0) atomicAdd(&degL[p0 >> 16], 1.f);
    }
    __syncthreads();
    size_t obase = (size_t)(gbase + dlo) * 64;
    for (int k = tid; k < 128*64; k += 1024) agg[obase + k] = accL[k];
    if (tid < 128) deg[gbase + dlo + tid] = degL[tid];
}

// ---- Kernel 3: fused epilogue + transpose:
//      x_aux = relu(h + agg/max(deg,1) + b); sq = ||x_aux||^2; xtg = x_aux^T ----
__global__ __launch_bounds__(256) void k_epitr(
    const float* __restrict__ h, const float* __restrict__ agg,
    const float* __restrict__ deg, const float* __restrict__ bias,
    float* __restrict__ xaux, float* __restrict__ sqv, float* __restrict__ xtg)
{
    __shared__ float tl[64*65];
    int tid = threadIdx.x;
    int n0 = blockIdx.x * 64;
    int w = tid >> 6, l = tid & 63;
    #pragma unroll
    for (int k = 0; k < 16; ++k) {
        int n = k*4 + w;                         // local node, wave-uniform
        float dg = fmaxf(deg[n0 + n], 1.f);
        size_t ge = (size_t)(n0 + n)*64 + l;
        float v = h[ge] + agg[ge] / dg + bias[l];
        v = fmaxf(v, 0.f);
        xaux[ge] = v;
        float s = wsum(v*v);
        if (l == 0) sqv[n0 + n] = s;
        tl[n*65 + l] = v;
    }
    __syncthreads();
    #pragma unroll
    for (int k = 0; k < 16; ++k) {
        int f = tid + k*256;
        xtg[(size_t)(f >> 6)*NNODE + n0 + (f & 63)] = tl[(f & 63)*65 + (f >> 6)];
    }
}

// ---------------- Kernel 4: fused pairwise distance + noise + LN-ish + entmax15 ----------------
// 16 rows/block, 512 threads (8 waves). GEMM layout: wave = 256-col strip, lane = 4 cols,
// acc[16][4]. Transition through 32KB LDS in 4 rounds of 4 rows, interleaved with two
// entmax passes so only one z[8][4] is live at a time. Wave w owns rows {w, w+8}.
// __launch_bounds__(512, 2): round-6 profile showed (512,4) capped VGPR at 64 ->
// acc[16][4] spilled to scratch (+350MB WRITE, +92MB FETCH). (512,2) gives the
// allocator >=128 VGPRs under either 2nd-arg interpretation; live set ~95 fits.
#define PFMA(R, XI) { float xs_ = (XI); acc[R][0] += xs_*xj.x; acc[R][1] += xs_*xj.y; acc[R][2] += xs_*xj.z; acc[R][3] += xs_*xj.w; }

__device__ __forceinline__ void entmax_row(
    float (&z)[8][4], int l, size_t ro, float* __restrict__ outA, float* __restrict__ outL)
{
    // row stats: mu, sd, max (on logits held in z)
    float s = 0.f;
    #pragma unroll
    for (int k = 0; k < 8; ++k) { s += z[k][0]; s += z[k][1]; s += z[k][2]; s += z[k][3]; }
    s = wsum(s);
    float mu = s * (1.f/2048.f);
    float vs = 0.f;
    #pragma unroll
    for (int k = 0; k < 8; ++k) {
        #pragma unroll
        for (int c = 0; c < 4; ++c) { float t = z[k][c] - mu; vs += t*t; }
    }
    vs = wsum(vs);
    float sd = sqrtf(vs * (1.f/2048.f));
    float mx = -1e30f;
    #pragma unroll
    for (int k = 0; k < 8; ++k) {
        #pragma unroll
        for (int c = 0; c < 4; ++c) mx = fmaxf(mx, z[k][c]);
    }
    mx = wmax(mx);

    // z = 0.5*GAMMA*(lg - mu)/(sd+1e-5) - max(...) == cc*(lg - lgmax)
    float cc = 2.5f / (sd + 1e-5f);
    #pragma unroll
    for (int k = 0; k < 8; ++k) {
        #pragma unroll
        for (int c = 0; c < 4; ++c) z[k][c] = cc * (z[k][c] - mx);
    }

    // candidate extraction: only z > -1 can be in support (tau* >= zmax-1 = -1)
    float c0=-2.f, c1=-2.f, c2=-2.f, c3=-2.f; int cnt = 0;
    #pragma unroll
    for (int k = 0; k < 8; ++k) {
        #pragma unroll
        for (int c = 0; c < 4; ++c) {
            float zv = z[k][c];
            bool p = zv > -1.f;
            c3 = p ? c2 : c3; c2 = p ? c1 : c2; c1 = p ? c0 : c1; c0 = p ? zv : c0;
            cnt += p ? 1 : 0;
        }
    }
    unsigned long long ovf = __ballot(cnt > 4);

    // bisection on S(tau) = sum max(z-tau,0)^2 = 1, tau in [-1, 0]
    float lo = -1.f, hi = 0.f;
    if (ovf == 0ull) {
        for (int it = 0; it < 25; ++it) {
            float mid = 0.5f*(lo+hi);
            float p, S;
            p = fmaxf(c0-mid,0.f); S  = p*p;
            p = fmaxf(c1-mid,0.f); S += p*p;
            p = fmaxf(c2-mid,0.f); S += p*p;
            p = fmaxf(c3-mid,0.f); S += p*p;
            S = wsum(S);
            bool ge = S >= 1.f;
            lo = ge ? mid : lo; hi = ge ? hi : mid;
        }
    } else {
        for (int it = 0; it < 25; ++it) {
            float mid = 0.5f*(lo+hi);
            float S = 0.f;
            #pragma unroll
            for (int k = 0; k < 8; ++k) {
                #pragma unroll
                for (int c = 0; c < 4; ++c) { float p = fmaxf(z[k][c]-mid, 0.f); S += p*p; }
            }
            S = wsum(S);
            bool ge = S >= 1.f;
            lo = ge ? mid : lo; hi = ge ? hi : mid;
        }
    }
    float tmid = 0.5f*(lo+hi);

    // exact tau from identified support (reference's closed form)
    float k1 = 0.f, s1 = 0.f, q1 = 0.f;
    if (ovf == 0ull) {
        bool in;
        in = c0 > tmid; k1 += in?1.f:0.f; s1 += in?c0:0.f; q1 += in?c0*c0:0.f;
        in = c1 > tmid; k1 += in?1.f:0.f; s1 += in?c1:0.f; q1 += in?c1*c1:0.f;
        in = c2 > tmid; k1 += in?1.f:0.f; s1 += in?c2:0.f; q1 += in?c2*c2:0.f;
        in = c3 > tmid; k1 += in?1.f:0.f; s1 += in?c3:0.f; q1 += in?c3*c3:0.f;
    } else {
        #pragma unroll
        for (int k = 0; k < 8; ++k) {
            #pragma unroll
            for (int c = 0; c < 4; ++c) {
                float zv = z[k][c];
                bool in = zv > tmid;
                k1 += in?1.f:0.f; s1 += in?zv:0.f; q1 += in?zv*zv:0.f;
            }
        }
    }
    k1 = wsum(k1); s1 = wsum(s1); q1 = wsum(q1);
    float kin  = 1.f / k1;
    float mean = s1 * kin;
    float ssv  = q1 - s1*s1*kin;
    float tau  = mean - sqrtf(fmaxf((1.f - ssv)*kin, 0.f));

    // outputs: A = clip(z - tau, 0)^2 ; logprobs = log(A + 1e-6); non-temporal (write-once)
    #pragma unroll
    for (int k = 0; k < 8; ++k) {
        float p;
        f32x4 a, lg;
        p = fmaxf(z[k][0]-tau, 0.f); a.x = p*p;
        p = fmaxf(z[k][1]-tau, 0.f); a.y = p*p;
        p = fmaxf(z[k][2]-tau, 0.f); a.z = p*p;
        p = fmaxf(z[k][3]-tau, 0.f); a.w = p*p;
        lg.x = __logf(a.x+1e-6f); lg.y = __logf(a.y+1e-6f);
        lg.z = __logf(a.z+1e-6f); lg.w = __logf(a.w+1e-6f);
        __builtin_nontemporal_store(a,  (f32x4*)&outA[ro + k*256 + (l << 2)]);
        __builtin_nontemporal_store(lg, (f32x4*)&outL[ro + k*256 + (l << 2)]);
    }
}

__global__ __launch_bounds__(512, 2) void k_pair(
    const float* __restrict__ xtg, const float* __restrict__ xaux,
    const float* __restrict__ sq, const float* __restrict__ noise,
    float* __restrict__ outA, float* __restrict__ outL)
{
    __shared__ float buf[4*2048];    // 32 KB transition buffer
    __shared__ float xit[64*16];     // 4 KB, d-major: xit[d*16 + r]
    __shared__ float sqi[16];
    int tid = threadIdx.x;
    int b  = blockIdx.x >> 7;        // 128 row-blocks per graph
    int r0 = (blockIdx.x & 127) << 4;
    {
        int e = tid;                 // e = d*16 + r
        xit[e] = xaux[(size_t)(b*NPG + r0 + (e & 15))*64 + (e >> 4)];
        e = tid + 512;
        xit[e] = xaux[(size_t)(b*NPG + r0 + (e & 15))*64 + (e >> 4)];
        if (tid < 16) sqi[tid] = sq[b*NPG + r0 + tid];
    }
    __syncthreads();
    int w = tid >> 6, l = tid & 63;
    int jb = b*NPG + (w << 8) + (l << 2);

    float acc[16][4];
    #pragma unroll
    for (int r = 0; r < 16; ++r) { acc[r][0]=0.f; acc[r][1]=0.f; acc[r][2]=0.f; acc[r][3]=0.f; }

    const float* xp = xtg + jb;
    #pragma unroll 2
    for (int d = 0; d < 64; ++d) {
        float4 xj = *(const float4*)(xp + (size_t)d*NNODE);
        const float4* xi = (const float4*)&xit[d*16];
        float4 x0 = xi[0], x1 = xi[1], x2 = xi[2], x3 = xi[3];
        PFMA( 0,x0.x) PFMA( 1,x0.y) PFMA( 2,x0.z) PFMA( 3,x0.w)
        PFMA( 4,x1.x) PFMA( 5,x1.y) PFMA( 6,x1.z) PFMA( 7,x1.w)
        PFMA( 8,x2.x) PFMA( 9,x2.y) PFMA(10,x2.z) PFMA(11,x2.w)
        PFMA(12,x3.x) PFMA(13,x3.y) PFMA(14,x3.z) PFMA(15,x3.w)
    }

    // logits = -sqrt(clip(sq_i + sq_j - 2*dot, 0) + 1e-12) + noise (in-place in acc)
    float4 sj = *(const float4*)&sq[jb];
    #pragma unroll
    for (int r = 0; r < 16; ++r) {
        f32x4 nz = __builtin_nontemporal_load(
            (const f32x4*)(noise + (size_t)(b*NPG + r0 + r)*NPG + (w << 8) + (l << 2)));
        float si = sqi[r];
        acc[r][0] = nz.x - sqrtf(fmaxf(si + sj.x - 2.f*acc[r][0], 0.f) + 1e-12f);
        acc[r][1] = nz.y - sqrtf(fmaxf(si + sj.y - 2.f*acc[r][1], 0.f) + 1e-12f);
        acc[r][2] = nz.z - sqrtf(fmaxf(si + sj.z - 2.f*acc[r][2], 0.f) + 1e-12f);
        acc[r][3] = nz.w - sqrtf(fmaxf(si + sj.w - 2.f*acc[r][3], 0.f) + 1e-12f);
    }

    int col = (w << 8) + (l << 2);
    int wr = w & 3;
    float z[8][4];

    // round 0: rows 0-3 -> waves 0-3
    #pragma unroll
    for (int r = 0; r < 4; ++r)
        *(float4*)&buf[r*2048 + col] = make_float4(acc[r][0],acc[r][1],acc[r][2],acc[r][3]);
    __syncthreads();
    if (w < 4) {
        #pragma unroll
        for (int k = 0; k < 8; ++k) {
            float4 t = *(const float4*)&buf[wr*2048 + k*256 + (l << 2)];
            z[k][0]=t.x; z[k][1]=t.y; z[k][2]=t.z; z[k][3]=t.w;
        }
    }
    __syncthreads();
    // round 1: rows 4-7 -> waves 4-7
    #pragma unroll
    for (int r = 0; r < 4; ++r)
        *(float4*)&buf[r*2048 + col] = make_float4(acc[r+4][0],acc[r+4][1],acc[r+4][2],acc[r+4][3]);
    __syncthreads();
    if (w >= 4) {
        #pragma unroll
        for (int k = 0; k < 8; ++k) {
            float4 t = *(const float4*)&buf[wr*2048 + k*256 + (l << 2)];
            z[k][0]=t.x; z[k][1]=t.y; z[k][2]=t.z; z[k][3]=t.w;
        }
    }
    __syncthreads();
    // entmax pass 1: wave w handles row r0+w (registers + global only)
    entmax_row(z, l, (size_t)(b*NPG + r0 + w) * NPG, outA, outL);

    // round 2: rows 8-11 -> waves 0-3
    #pragma unroll
    for (int r = 0; r < 4; ++r)
        *(float4*)&buf[r*2048 + col] = make_float4(acc[r+8][0],acc[r+8][1],acc[r+8][2],acc[r+8][3]);
    __syncthreads();
    if (w < 4) {
        #pragma unroll
        for (int k = 0; k < 8; ++k) {
            float4 t = *(const float4*)&buf[wr*2048 + k*256 + (l << 2)];
            z[k][0]=t.x; z[k][1]=t.y; z[k][2]=t.z; z[k][3]=t.w;
        }
    }
    __syncthreads();
    // round 3: rows 12-15 -> waves 4-7
    #pragma unroll
    for (int r = 0; r < 4; ++r)
        *(float4*)&buf[r*2048 + col] = make_float4(acc[r+12][0],acc[r+12][1],acc[r+12][2],acc[r+12][3]);
    __syncthreads();
    if (w >= 4) {
        #pragma unroll
        for (int k = 0; k < 8; ++k) {
            float4 t = *(const float4*)&buf[wr*2048 + k*256 + (l << 2)];
            z[k][0]=t.x; z[k][1]=t.y; z[k][2]=t.z; z[k][3]=t.w;
        }
    }
    // entmax pass 2: wave w handles row r0+8+w
    entmax_row(z, l, (size_t)(b*NPG + r0 + 8 + w) * NPG, outA, outL);
}

// ---------------- host ----------------
extern "C" void kernel_launch(void* const* d_in, const int* in_sizes, int n_in,
                              void* d_out, int out_size, void* d_ws, size_t ws_size,
                              hipStream_t stream)
{
    (void)in_sizes; (void)n_in; (void)out_size; (void)ws_size;
    const float* x     = (const float*)d_in[0];
    const int*   ei    = (const int*)d_in[1];
    const float* Wself = (const float*)d_in[4];
    const float* Wnei  = (const float*)d_in[5];
    const float* bias  = (const float*)d_in[6];
    const float* noise = (const float*)d_in[7];
    float* out = (float*)d_out;
    float* ws  = (float*)d_ws;

    // ws layout (floats), peak ~33.8 MB: h xn agg deg sq xtg
    float* h    = ws;
    float* xn   = ws + 2097152;
    float* agg  = ws + 4194304;
    float* deg  = ws + 6291456;
    float* sqv  = ws + 6324224;
    float* xtg  = ws + 6356992;

    float* xaux = out;                 // [32768][64]
    float* outA = out + 2097152;       // [16][2048][2048]
    float* outL = out + 69206016;      // [16][2048][2048]

    hipLaunchKernelGGL(k_inproj, dim3(1024), dim3(256),  0, stream, x, Wself, Wnei, h, xn);
    hipLaunchKernelGGL(k_agg,    dim3(256),  dim3(1024), 0, stream, ei, xn, agg, deg);
    hipLaunchKernelGGL(k_epitr,  dim3(512),  dim3(256),  0, stream, h, agg, deg, bias, xaux, sqv, xtg);
    hipLaunchKernelGGL(k_pair,   dim3(2048), dim3(512),  0, stream, xtg, xaux, sqv, noise, outA, outL);
}

// Round 11
// 1082.652 us; speedup vs baseline: 1.0950x; 1.0605x over previous
//
#include <hip/hip_runtime.h>

#define NGRAPH 16
#define NPG    2048
#define NNODE  (NGRAPH*NPG)      // 32768
#define DIN    128
#define DEMB   64
#define NEDGE  (NNODE*16)        // 524288
#define QCAP   4096

typedef float f32x4 __attribute__((ext_vector_type(4)));

__device__ __forceinline__ float wsum(float v) {
    #pragma unroll
    for (int m = 1; m < 64; m <<= 1) v += __shfl_xor(v, m, 64);
    return v;
}
__device__ __forceinline__ float wmax(float v) {
    #pragma unroll
    for (int m = 1; m < 64; m <<= 1) v = fmaxf(v, __shfl_xor(v, m, 64));
    return v;
}

// ---------------- Kernel 1: h = x@W_self, xn = x@W_nei ----------------
__global__ __launch_bounds__(256) void k_inproj(
    const float* __restrict__ x, const float* __restrict__ Wself,
    const float* __restrict__ Wnei, float* __restrict__ h, float* __restrict__ xn)
{
    __shared__ float ws[DIN*DEMB];   // 32 KB
    __shared__ float wn[DIN*DEMB];   // 32 KB
    int tid = threadIdx.x;
    int n0 = blockIdx.x * 32;
    #pragma unroll
    for (int k = 0; k < 8; ++k) {
        ((float4*)ws)[tid + k*256] = ((const float4*)Wself)[tid + k*256];
        ((float4*)wn)[tid + k*256] = ((const float4*)Wnei)[tid + k*256];
    }
    __syncthreads();
    int nl = tid >> 3, og = (tid & 7) * 8;
    const float* xr = x + (size_t)(n0 + nl) * DIN;
    float ah[8] = {0,0,0,0,0,0,0,0};
    float an[8] = {0,0,0,0,0,0,0,0};
    for (int d4 = 0; d4 < DIN/4; ++d4) {
        float4 xv = *(const float4*)(xr + d4*4);
        #pragma unroll
        for (int dd = 0; dd < 4; ++dd) {
            float xs = (dd==0)?xv.x:(dd==1)?xv.y:(dd==2)?xv.z:xv.w;
            int d = d4*4 + dd;
            float4 a = *(const float4*)&ws[d*DEMB + og];
            float4 b = *(const float4*)&ws[d*DEMB + og + 4];
            ah[0] += xs*a.x; ah[1] += xs*a.y; ah[2] += xs*a.z; ah[3] += xs*a.w;
            ah[4] += xs*b.x; ah[5] += xs*b.y; ah[6] += xs*b.z; ah[7] += xs*b.w;
            float4 c = *(const float4*)&wn[d*DEMB + og];
            float4 e = *(const float4*)&wn[d*DEMB + og + 4];
            an[0] += xs*c.x; an[1] += xs*c.y; an[2] += xs*c.z; an[3] += xs*c.w;
            an[4] += xs*e.x; an[5] += xs*e.y; an[6] += xs*e.z; an[7] += xs*e.w;
        }
    }
    size_t o = (size_t)(n0 + nl)*DEMB + og;
    *(float4*)&h[o]    = make_float4(ah[0],ah[1],ah[2],ah[3]);
    *(float4*)&h[o+4]  = make_float4(ah[4],ah[5],ah[6],ah[7]);
    *(float4*)&xn[o]   = make_float4(an[0],an[1],an[2],an[3]);
    *(float4*)&xn[o+4] = make_float4(an[4],an[5],an[6],an[7]);
}

// ---------------- Kernel 2: edge aggregation, LDS-binned (no global atomics) ----------------
__global__ __launch_bounds__(1024) void k_agg(
    const int* __restrict__ ei, const float* __restrict__ xn,
    float* __restrict__ agg, float* __restrict__ deg)
{
    __shared__ float accL[128*64];   // 32 KB
    __shared__ float degL[128];
    __shared__ int   queue[QCAP];    // 16 KB
    __shared__ int   qcnt;
    int tid = threadIdx.x;
    int g   = blockIdx.x >> 4;       // graph
    int dlo = (blockIdx.x & 15) * 128;
    for (int k = tid; k < 128*64; k += 1024) accL[k] = 0.f;
    if (tid < 128) degL[tid] = 0.f;
    if (tid == 0) qcnt = 0;
    __syncthreads();
    int e0 = g * (NPG*16);
    int gbase = g * NPG;
    for (int k = 0; k < 32; ++k) {
        int e = e0 + k*1024 + tid;
        int dst = ei[NEDGE + e];
        int dl = dst - gbase - dlo;
        if ((unsigned)dl < 128u) {
            int src = ei[e];                 // global node id < 32768, fits 16 bits
            int qi = atomicAdd(&qcnt, 1);
            if (qi < QCAP) queue[qi] = (dl << 16) | src;
        }
    }
    __syncthreads();
    int qn = qcnt < QCAP ? qcnt : QCAP;
    int w = tid >> 6, l = tid & 63;
    int i = w;
    // 8-deep gather pipeline for latency hiding
    for (; i + 112 < qn; i += 128) {
        int p[8]; float v[8];
        #pragma unroll
        for (int k = 0; k < 8; ++k) p[k] = queue[i + 16*k];
        #pragma unroll
        for (int k = 0; k < 8; ++k) v[k] = xn[(size_t)(p[k] & 0xffff)*64 + l];
        #pragma unroll
        for (int k = 0; k < 8; ++k) {
            atomicAdd(&accL[(p[k] >> 16)*64 + l], v[k]);
            if (l == 0) atomicAdd(&degL[p[k] >> 16], 1.f);
        }
    }
    for (; i < qn; i += 16) {
        int p0 = queue[i];
        float v0 = xn[(size_t)(p0 & 0xffff)*64 + l];
        atomicAdd(&accL[(p0 >> 16)*64 + l], v0);
        if (l == 0) atomicAdd(&degL[p0 >> 16], 1.f);
    }
    __syncthreads();
    size_t obase = (size_t)(gbase + dlo) * 64;
    for (int k = tid; k < 128*64; k += 1024) agg[obase + k] = accL[k];
    if (tid < 128) deg[gbase + dlo + tid] = degL[tid];
}

// ---- Kernel 3: fused epilogue + transpose:
//      x_aux = relu(h + agg/max(deg,1) + b); sq = ||x_aux||^2; xtg = x_aux^T ----
__global__ __launch_bounds__(256) void k_epitr(
    const float* __restrict__ h, const float* __restrict__ agg,
    const float* __restrict__ deg, const float* __restrict__ bias,
    float* __restrict__ xaux, float* __restrict__ sqv, float* __restrict__ xtg)
{
    __shared__ float tl[64*65];
    int tid = threadIdx.x;
    int n0 = blockIdx.x * 64;
    int w = tid >> 6, l = tid & 63;
    #pragma unroll
    for (int k = 0; k < 16; ++k) {
        int n = k*4 + w;                         // local node, wave-uniform
        float dg = fmaxf(deg[n0 + n], 1.f);
        size_t ge = (size_t)(n0 + n)*64 + l;
        float v = h[ge] + agg[ge] / dg + bias[l];
        v = fmaxf(v, 0.f);
        xaux[ge] = v;
        float s = wsum(v*v);
        if (l == 0) sqv[n0 + n] = s;
        tl[n*65 + l] = v;
    }
    __syncthreads();
    #pragma unroll
    for (int k = 0; k < 16; ++k) {
        int f = tid + k*256;
        xtg[(size_t)(f >> 6)*NNODE + n0 + (f & 63)] = tl[(f & 63)*65 + (f >> 6)];
    }
}

// ---------------- Kernel 4: fused pairwise distance + noise + LN-ish + entmax15 ----------------
// 16 rows/block, 512 threads (8 waves). GEMM layout: wave = 256-col strip, lane = 4 cols,
// acc[16][4]. Transition through 32KB LDS in 4 rounds of 4 rows, interleaved with two
// entmax passes so only one z[8][4] is live at a time. Wave w owns rows {w, w+8}.
// __launch_bounds__(512, 2): (512,4) capped VGPR at 64 -> acc spilled (round 6/8 A/B).
// entmax: direct closed-form solve on the <=4 global support candidates (z > -1);
// bisection+wsum retained only as rare fallback. Candidate count from 2 ballots.
#define PFMA(R, XI) { float xs_ = (XI); acc[R][0] += xs_*xj.x; acc[R][1] += xs_*xj.y; acc[R][2] += xs_*xj.z; acc[R][3] += xs_*xj.w; }

__device__ __forceinline__ void entmax_row(
    float (&z)[8][4], int l, size_t ro, float* __restrict__ outA, float* __restrict__ outL)
{
    // row stats: mu, sd, max (on logits held in z)
    float s = 0.f;
    #pragma unroll
    for (int k = 0; k < 8; ++k) { s += z[k][0]; s += z[k][1]; s += z[k][2]; s += z[k][3]; }
    s = wsum(s);
    float mu = s * (1.f/2048.f);
    float vs = 0.f;
    #pragma unroll
    for (int k = 0; k < 8; ++k) {
        #pragma unroll
        for (int c = 0; c < 4; ++c) { float t = z[k][c] - mu; vs += t*t; }
    }
    vs = wsum(vs);
    float sd = sqrtf(vs * (1.f/2048.f));
    float mx = -1e30f;
    #pragma unroll
    for (int k = 0; k < 8; ++k) {
        #pragma unroll
        for (int c = 0; c < 4; ++c) mx = fmaxf(mx, z[k][c]);
    }
    mx = wmax(mx);

    // z = 0.5*GAMMA*(lg - mu)/(sd+1e-5) - max(...) == cc*(lg - lgmax)
    float cc = 2.5f / (sd + 1e-5f);
    #pragma unroll
    for (int k = 0; k < 8; ++k) {
        #pragma unroll
        for (int c = 0; c < 4; ++c) z[k][c] = cc * (z[k][c] - mx);
    }

    // top-2 per lane among candidates (z > -1; tau* >= zmax-1 = -1)
    float c0 = -2.f, c1 = -2.f; int cnt = 0;
    #pragma unroll
    for (int k = 0; k < 8; ++k) {
        #pragma unroll
        for (int c = 0; c < 4; ++c) {
            float zv = z[k][c];
            bool p = zv > -1.f;
            cnt += p ? 1 : 0;
            float hi = fmaxf(c0, zv), lo = fminf(c0, zv);
            c0 = p ? hi : c0;
            c1 = p ? fmaxf(c1, lo) : c1;
        }
    }
    unsigned long long b1 = __ballot(cnt >= 1);
    unsigned long long b2 = __ballot(cnt >= 2);
    unsigned long long b3 = __ballot(cnt >= 3);
    int Kr = __popcll(b1) + __popcll(b2);

    float tau;
    if (b3 == 0ull && Kr <= 4) {
        // FAST PATH: gather the <=4 candidates to every lane, evaluate the
        // reference's sort-based cumulative formula for k=1..4 directly.
        float v0=-2.f, v1=-2.f, v2=-2.f, v3=-2.f; int n = 0;
        unsigned long long m = b1;
        while (m) {
            int ln = (int)__builtin_ctzll(m); m &= m - 1;
            float a = __shfl(c0, ln);
            v3 = (n==3)?a:v3; v2 = (n==2)?a:v2; v1 = (n==1)?a:v1; v0 = (n==0)?a:v0;
            ++n;
        }
        m = b2;
        while (m) {
            int ln = (int)__builtin_ctzll(m); m &= m - 1;
            float a = __shfl(c1, ln);
            v3 = (n==3)?a:v3; v2 = (n==2)?a:v2; v1 = (n==1)?a:v1; v0 = (n==0)?a:v0;
            ++n;
        }
        // sort descending (4-element network)
        float t;
        t=fmaxf(v0,v1); v1=fminf(v0,v1); v0=t;
        t=fmaxf(v2,v3); v3=fminf(v2,v3); v2=t;
        t=fmaxf(v0,v2); v2=fminf(v0,v2); v0=t;
        t=fmaxf(v1,v3); v3=fminf(v1,v3); v1=t;
        t=fmaxf(v1,v2); v2=fminf(v1,v2); v1=t;
        // cumulative closed form (matches reference arithmetic on top-k)
        float cs2=v0+v1, cs3=cs2+v2, cs4=cs3+v3;
        float cq1=v0*v0, cq2=cq1+v1*v1, cq3=cq2+v2*v2, cq4=cq3+v3*v3;
        float m1=v0,          q1=cq1;
        float m2=cs2*0.5f,    q2=cq2*0.5f;
        float m3=cs3*(1.f/3.f), q3=cq3*(1.f/3.f);
        float m4=cs4*0.25f,   q4=cq4*0.25f;
        float ss1=1.f*(q1-m1*m1), ss2=2.f*(q2-m2*m2), ss3=3.f*(q3-m3*m3), ss4=4.f*(q4-m4*m4);
        float ta1=m1-sqrtf(fmaxf((1.f-ss1)      ,0.f));
        float ta2=m2-sqrtf(fmaxf((1.f-ss2)*0.5f ,0.f));
        float ta3=m3-sqrtf(fmaxf((1.f-ss3)*(1.f/3.f),0.f));
        float ta4=m4-sqrtf(fmaxf((1.f-ss4)*0.25f,0.f));
        // support count, gated to real candidates (sentinels inert)
        int sp = 0;
        sp += (ta1 <= v0 && 1 <= Kr) ? 1 : 0;
        sp += (ta2 <= v1 && 2 <= Kr) ? 1 : 0;
        sp += (ta3 <= v2 && 3 <= Kr) ? 1 : 0;
        sp += (ta4 <= v3 && 4 <= Kr) ? 1 : 0;
        tau = (sp==4) ? ta4 : (sp==3) ? ta3 : (sp==2) ? ta2 : ta1;
    } else {
        // SLOW PATH (rare): bisection over full z + exact tau from support
        float lo = -1.f, hi = 0.f;
        for (int it = 0; it < 25; ++it) {
            float mid = 0.5f*(lo+hi);
            float S = 0.f;
            #pragma unroll
            for (int k = 0; k < 8; ++k) {
                #pragma unroll
                for (int c = 0; c < 4; ++c) { float p = fmaxf(z[k][c]-mid, 0.f); S += p*p; }
            }
            S = wsum(S);
            bool ge = S >= 1.f;
            lo = ge ? mid : lo; hi = ge ? hi : mid;
        }
        float tmid = 0.5f*(lo+hi);
        float k1 = 0.f, s1 = 0.f, q1 = 0.f;
        #pragma unroll
        for (int k = 0; k < 8; ++k) {
            #pragma unroll
            for (int c = 0; c < 4; ++c) {
                float zv = z[k][c];
                bool in = zv > tmid;
                k1 += in?1.f:0.f; s1 += in?zv:0.f; q1 += in?zv*zv:0.f;
            }
        }
        k1 = wsum(k1); s1 = wsum(s1); q1 = wsum(q1);
        float kin  = 1.f / k1;
        float mean = s1 * kin;
        float ssv  = q1 - s1*s1*kin;
        tau = mean - sqrtf(fmaxf((1.f - ssv)*kin, 0.f));
    }

    // outputs: A = clip(z - tau, 0)^2 ; logprobs = log(A + 1e-6); non-temporal (write-once)
    #pragma unroll
    for (int k = 0; k < 8; ++k) {
        float p;
        f32x4 a, lg;
        p = fmaxf(z[k][0]-tau, 0.f); a.x = p*p;
        p = fmaxf(z[k][1]-tau, 0.f); a.y = p*p;
        p = fmaxf(z[k][2]-tau, 0.f); a.z = p*p;
        p = fmaxf(z[k][3]-tau, 0.f); a.w = p*p;
        lg.x = __logf(a.x+1e-6f); lg.y = __logf(a.y+1e-6f);
        lg.z = __logf(a.z+1e-6f); lg.w = __logf(a.w+1e-6f);
        __builtin_nontemporal_store(a,  (f32x4*)&outA[ro + k*256 + (l << 2)]);
        __builtin_nontemporal_store(lg, (f32x4*)&outL[ro + k*256 + (l << 2)]);
    }
}

__global__ __launch_bounds__(512, 2) void k_pair(
    const float* __restrict__ xtg, const float* __restrict__ xaux,
    const float* __restrict__ sq, const float* __restrict__ noise,
    float* __restrict__ outA, float* __restrict__ outL)
{
    __shared__ float buf[4*2048];    // 32 KB transition buffer
    __shared__ float xit[64*16];     // 4 KB, d-major: xit[d*16 + r]
    __shared__ float sqi[16];
    int tid = threadIdx.x;
    int b  = blockIdx.x >> 7;        // 128 row-blocks per graph
    int r0 = (blockIdx.x & 127) << 4;
    {
        int e = tid;                 // e = d*16 + r
        xit[e] = xaux[(size_t)(b*NPG + r0 + (e & 15))*64 + (e >> 4)];
        e = tid + 512;
        xit[e] = xaux[(size_t)(b*NPG + r0 + (e & 15))*64 + (e >> 4)];
        if (tid < 16) sqi[tid] = sq[b*NPG + r0 + tid];
    }
    __syncthreads();
    int w = tid >> 6, l = tid & 63;
    int jb = b*NPG + (w << 8) + (l << 2);

    float acc[16][4];
    #pragma unroll
    for (int r = 0; r < 16; ++r) { acc[r][0]=0.f; acc[r][1]=0.f; acc[r][2]=0.f; acc[r][3]=0.f; }

    const float* xp = xtg + jb;
    #pragma unroll 2
    for (int d = 0; d < 64; ++d) {
        float4 xj = *(const float4*)(xp + (size_t)d*NNODE);
        const float4* xi = (const float4*)&xit[d*16];
        float4 x0 = xi[0], x1 = xi[1], x2 = xi[2], x3 = xi[3];
        PFMA( 0,x0.x) PFMA( 1,x0.y) PFMA( 2,x0.z) PFMA( 3,x0.w)
        PFMA( 4,x1.x) PFMA( 5,x1.y) PFMA( 6,x1.z) PFMA( 7,x1.w)
        PFMA( 8,x2.x) PFMA( 9,x2.y) PFMA(10,x2.z) PFMA(11,x2.w)
        PFMA(12,x3.x) PFMA(13,x3.y) PFMA(14,x3.z) PFMA(15,x3.w)
    }

    // logits = -sqrt(clip(sq_i + sq_j - 2*dot, 0) + 1e-12) + noise (in-place in acc)
    float4 sj = *(const float4*)&sq[jb];
    #pragma unroll
    for (int r = 0; r < 16; ++r) {
        f32x4 nz = __builtin_nontemporal_load(
            (const f32x4*)(noise + (size_t)(b*NPG + r0 + r)*NPG + (w << 8) + (l << 2)));
        float si = sqi[r];
        acc[r][0] = nz.x - sqrtf(fmaxf(si + sj.x - 2.f*acc[r][0], 0.f) + 1e-12f);
        acc[r][1] = nz.y - sqrtf(fmaxf(si + sj.y - 2.f*acc[r][1], 0.f) + 1e-12f);
        acc[r][2] = nz.z - sqrtf(fmaxf(si + sj.z - 2.f*acc[r][2], 0.f) + 1e-12f);
        acc[r][3] = nz.w - sqrtf(fmaxf(si + sj.w - 2.f*acc[r][3], 0.f) + 1e-12f);
    }

    int col = (w << 8) + (l << 2);
    int wr = w & 3;
    float z[8][4];

    // round 0: rows 0-3 -> waves 0-3
    #pragma unroll
    for (int r = 0; r < 4; ++r)
        *(float4*)&buf[r*2048 + col] = make_float4(acc[r][0],acc[r][1],acc[r][2],acc[r][3]);
    __syncthreads();
    if (w < 4) {
        #pragma unroll
        for (int k = 0; k < 8; ++k) {
            float4 t = *(const float4*)&buf[wr*2048 + k*256 + (l << 2)];
            z[k][0]=t.x; z[k][1]=t.y; z[k][2]=t.z; z[k][3]=t.w;
        }
    }
    __syncthreads();
    // round 1: rows 4-7 -> waves 4-7
    #pragma unroll
    for (int r = 0; r < 4; ++r)
        *(float4*)&buf[r*2048 + col] = make_float4(acc[r+4][0],acc[r+4][1],acc[r+4][2],acc[r+4][3]);
    __syncthreads();
    if (w >= 4) {
        #pragma unroll
        for (int k = 0; k < 8; ++k) {
            float4 t = *(const float4*)&buf[wr*2048 + k*256 + (l << 2)];
            z[k][0]=t.x; z[k][1]=t.y; z[k][2]=t.z; z[k][3]=t.w;
        }
    }
    __syncthreads();
    // entmax pass 1: wave w handles row r0+w (registers + global only)
    entmax_row(z, l, (size_t)(b*NPG + r0 + w) * NPG, outA, outL);

    // round 2: rows 8-11 -> waves 0-3
    #pragma unroll
    for (int r = 0; r < 4; ++r)
        *(float4*)&buf[r*2048 + col] = make_float4(acc[r+8][0],acc[r+8][1],acc[r+8][2],acc[r+8][3]);
    __syncthreads();
    if (w < 4) {
        #pragma unroll
        for (int k = 0; k < 8; ++k) {
            float4 t = *(const float4*)&buf[wr*2048 + k*256 + (l << 2)];
            z[k][0]=t.x; z[k][1]=t.y; z[k][2]=t.z; z[k][3]=t.w;
        }
    }
    __syncthreads();
    // round 3: rows 12-15 -> waves 4-7
    #pragma unroll
    for (int r = 0; r < 4; ++r)
        *(float4*)&buf[r*2048 + col] = make_float4(acc[r+12][0],acc[r+12][1],acc[r+12][2],acc[r+12][3]);
    __syncthreads();
    if (w >= 4) {
        #pragma unroll
        for (int k = 0; k < 8; ++k) {
            float4 t = *(const float4*)&buf[wr*2048 + k*256 + (l << 2)];
            z[k][0]=t.x; z[k][1]=t.y; z[k][2]=t.z; z[k][3]=t.w;
        }
    }
    // entmax pass 2: wave w handles row r0+8+w
    entmax_row(z, l, (size_t)(b*NPG + r0 + 8 + w) * NPG, outA, outL);
}

// ---------------- host ----------------
extern "C" void kernel_launch(void* const* d_in, const int* in_sizes, int n_in,
                              void* d_out, int out_size, void* d_ws, size_t ws_size,
                              hipStream_t stream)
{
    (void)in_sizes; (void)n_in; (void)out_size; (void)ws_size;
    const float* x     = (const float*)d_in[0];
    const int*   ei    = (const int*)d_in[1];
    const float* Wself = (const float*)d_in[4];
    const float* Wnei  = (const float*)d_in[5];
    const float* bias  = (const float*)d_in[6];
    const float* noise = (const float*)d_in[7];
    float* out = (float*)d_out;
    float* ws  = (float*)d_ws;

    // ws layout (floats), peak ~33.8 MB: h xn agg deg sq xtg
    float* h    = ws;
    float* xn   = ws + 2097152;
    float* agg  = ws + 4194304;
    float* deg  = ws + 6291456;
    float* sqv  = ws + 6324224;
    float* xtg  = ws + 6356992;

    float* xaux = out;                 // [32768][64]
    float* outA = out + 2097152;       // [16][2048][2048]
    float* outL = out + 69206016;      // [16][2048][2048]

    hipLaunchKernelGGL(k_inproj, dim3(1024), dim3(256),  0, stream, x, Wself, Wnei, h, xn);
    hipLaunchKernelGGL(k_agg,    dim3(256),  dim3(1024), 0, stream, ei, xn, agg, deg);
    hipLaunchKernelGGL(k_epitr,  dim3(512),  dim3(256),  0, stream, h, agg, deg, bias, xaux, sqv, xtg);
    hipLaunchKernelGGL(k_pair,   dim3(2048), dim3(512),  0, stream, xtg, xaux, sqv, noise, outA, outL);
}